// Round 6
// baseline (240.112 us; speedup 1.0000x reference)
//
#include <hip/hip_runtime.h>
#include <math.h>

// Problem: B=2, S=4096, D=512, H=4 (h-broadcast: out[b,h]=out[b,0])
// cast(+zero rowsum) -> proj(Q,V fused z=2) -> S-GEMM(+exp,+rowsum) -> PV32
#define SEQ 4096
#define DIM 512
#define NBATCH 2

typedef __bf16 bf16;
typedef __bf16 bf16x8 __attribute__((ext_vector_type(8)));
typedef __bf16 bf16x4 __attribute__((ext_vector_type(4)));
typedef float  f32x4  __attribute__((ext_vector_type(4)));
typedef float  f32x16 __attribute__((ext_vector_type(16)));

#define GLOAD_LDS16(g, l)                                                              \
  __builtin_amdgcn_global_load_lds((__attribute__((address_space(1))) void*)(g),       \
                                   (__attribute__((address_space(3))) void*)(l), 16, 0, 0)

#define VMCNT(n) asm volatile("s_waitcnt vmcnt(" #n ")" ::: "memory")

static const long NQ_ = (long)NBATCH * SEQ * DIM;  // 4,194,304
static const long NW_ = (long)DIM * DIM;           // 262,144
#define QSCALE 0.04419417382415922f                 // 1/sqrt(512)

// ---------------------------------------------------------------------------
// Fused f32 -> bf16 casts + rowsum zeroing
// ---------------------------------------------------------------------------
__device__ __forceinline__ void cvt4(const float* __restrict__ s, bf16* __restrict__ d) {
  f32x4 x = *(const f32x4*)s;
  bf16x4 y;
  y[0] = (bf16)x[0]; y[1] = (bf16)x[1]; y[2] = (bf16)x[2]; y[3] = (bf16)x[3];
  *(bf16x4*)d = y;
}

__global__ __launch_bounds__(256)
void cast5(const float* __restrict__ q, const float* __restrict__ k,
           const float* __restrict__ v, const float* __restrict__ Wq,
           const float* __restrict__ Wv,
           bf16* __restrict__ qb, bf16* __restrict__ kb, bf16* __restrict__ vb,
           bf16* __restrict__ wqb, bf16* __restrict__ wvb,
           float* __restrict__ rs) {
  long tid = blockIdx.x * 256L + threadIdx.x;
  long nth = gridDim.x * 256L;
  if (rs && tid < NBATCH * SEQ) rs[tid] = 0.0f;  // rowsum zero (non-aliased buf)
  for (long i = tid * 4; i < NQ_; i += nth * 4) {
    cvt4(q + i, qb + i);
    cvt4(k + i, kb + i);
    cvt4(v + i, vb + i);
  }
  for (long i = tid * 4; i < NW_; i += nth * 4) {
    cvt4(Wq + i, wqb + i);
    cvt4(Wv + i, wvb + i);
  }
}

__global__ __launch_bounds__(256)
void zero_f32(float* __restrict__ p, int n) {
  int i = blockIdx.x * 256 + threadIdx.x;
  if (i < n) p[i] = 0.0f;
}

// ---------------------------------------------------------------------------
// gemm3<BM,BN,OUT>: C[M,N] = A[M,K]*Bt[N,K]^T, BK=32, 512 thr = 8 waves 2Mx4N.
// 3 rotating LDS buffers, counted vmcnt, one barrier/tile (r5 structure).
// OUT=0: projections (z=0: Q=(acc+bq)*QSCALE row-major; z=1: Vt=(acc+bv) T).
// OUT=1: E=exp(acc) bf16 row-major + rowsum atomics.
// ---------------------------------------------------------------------------
template <int BM, int BN, int OUT>
__global__ __launch_bounds__(512, (BM == 256 ? 2 : 6))
void gemm3(const bf16* __restrict__ A, const bf16* __restrict__ Bt,
           void* __restrict__ Cv, const float* __restrict__ bias0,
           const float* __restrict__ bias1, float* __restrict__ rowsum,
           int N, int K, long sB) {
  constexpr int MF = BM / 32;
  constexpr int NF = BN / 64;
  constexpr int LA = BM / 128;
  constexpr int LB = BN / 128;
  constexpr int NLD = LA + LB;
  constexpr int ASZ = BM * 32;
  constexpr int BSZ = BN * 32;
  __shared__ __align__(16) bf16 lds[3][ASZ + BSZ];

  const int t = threadIdx.x;
  const int l = t & 63, w = t >> 6;
  const int lr = l & 15, lg = l >> 4;

  const unsigned bid = blockIdx.y * gridDim.x + blockIdx.x;
  const unsigned nwg = gridDim.x * gridDim.y;
  const unsigned q8 = nwg >> 3;
  const unsigned swz = (bid & 7) * q8 + (bid >> 3);
  const long m0 = (long)(swz % gridDim.x) * BM;
  const long n0 = (long)(swz / gridDim.x) * BN;

  const int z = blockIdx.z;
  if constexpr (OUT == 0) {
    A += (long)z * NQ_;
    Bt += (long)z * NW_;
  } else {
    Bt += (m0 >> 12) * sB;
  }

  const int wr = (w >> 2) * (BM / 2);
  const int wc = (w & 3) * (BN / 4);

  const bf16* gA[LA];
  const bf16* gB[LB];
#pragma unroll
  for (int i = 0; i < LA; ++i) {
    int s = i * 512 + t, row = s >> 2, c = (s & 3) ^ ((row >> 1) & 3);
    gA[i] = A + (m0 + row) * (long)K + c * 8;
  }
#pragma unroll
  for (int i = 0; i < LB; ++i) {
    int s = i * 512 + t, row = s >> 2, c = (s & 3) ^ ((row >> 1) & 3);
    gB[i] = Bt + (n0 + row) * (long)K + c * 8;
  }

  int offA[MF], offB[NF];
#pragma unroll
  for (int mf = 0; mf < MF; ++mf)
    offA[mf] = (wr + mf * 16 + lr) * 32 + ((lg ^ ((lr >> 1) & 3)) * 8);
#pragma unroll
  for (int nf = 0; nf < NF; ++nf)
    offB[nf] = ASZ + (wc + nf * 16 + lr) * 32 + ((lg ^ ((lr >> 1) & 3)) * 8);

  auto stage = [&](int tt, int bidx) {
    const long ko = (long)tt * 32;
#pragma unroll
    for (int i = 0; i < LA; ++i)
      GLOAD_LDS16(gA[i] + ko, &lds[bidx][(i * 512 + w * 64) * 8]);
#pragma unroll
    for (int i = 0; i < LB; ++i)
      GLOAD_LDS16(gB[i] + ko, &lds[bidx][ASZ + (i * 512 + w * 64) * 8]);
  };

  f32x4 acc[MF][NF] = {};
  const int NT = K >> 5;

  stage(0, 0);
  stage(1, 1);
  if constexpr (NLD == 4) VMCNT(4); else VMCNT(2);
  __builtin_amdgcn_sched_barrier(0);
  __builtin_amdgcn_s_barrier();
  __builtin_amdgcn_sched_barrier(0);

  int cur = 0, stg = 2;
  for (int tt = 0; tt < NT - 2; ++tt) {
    bf16x8 af[MF], bfn[NF];
#pragma unroll
    for (int mf = 0; mf < MF; ++mf) af[mf] = *(const bf16x8*)(&lds[cur][offA[mf]]);
#pragma unroll
    for (int nf = 0; nf < NF; ++nf) bfn[nf] = *(const bf16x8*)(&lds[cur][offB[nf]]);
    stage(tt + 2, stg);
    __builtin_amdgcn_s_setprio(1);
#pragma unroll
    for (int mf = 0; mf < MF; ++mf)
#pragma unroll
      for (int nf = 0; nf < NF; ++nf)
        acc[mf][nf] = __builtin_amdgcn_mfma_f32_16x16x32_bf16(af[mf], bfn[nf], acc[mf][nf], 0, 0, 0);
    __builtin_amdgcn_s_setprio(0);
    if constexpr (NLD == 4) VMCNT(4); else VMCNT(2);
    __builtin_amdgcn_sched_barrier(0);
    __builtin_amdgcn_s_barrier();
    __builtin_amdgcn_sched_barrier(0);
    cur = (cur == 2) ? 0 : cur + 1;
    stg = (stg == 2) ? 0 : stg + 1;
  }
  {
    bf16x8 af[MF], bfn[NF];
#pragma unroll
    for (int mf = 0; mf < MF; ++mf) af[mf] = *(const bf16x8*)(&lds[cur][offA[mf]]);
#pragma unroll
    for (int nf = 0; nf < NF; ++nf) bfn[nf] = *(const bf16x8*)(&lds[cur][offB[nf]]);
    __builtin_amdgcn_s_setprio(1);
#pragma unroll
    for (int mf = 0; mf < MF; ++mf)
#pragma unroll
      for (int nf = 0; nf < NF; ++nf)
        acc[mf][nf] = __builtin_amdgcn_mfma_f32_16x16x32_bf16(af[mf], bfn[nf], acc[mf][nf], 0, 0, 0);
    __builtin_amdgcn_s_setprio(0);
    VMCNT(0);
    __builtin_amdgcn_sched_barrier(0);
    __builtin_amdgcn_s_barrier();
    __builtin_amdgcn_sched_barrier(0);
    cur = (cur == 2) ? 0 : cur + 1;
  }
  {
    bf16x8 af[MF], bfn[NF];
#pragma unroll
    for (int mf = 0; mf < MF; ++mf) af[mf] = *(const bf16x8*)(&lds[cur][offA[mf]]);
#pragma unroll
    for (int nf = 0; nf < NF; ++nf) bfn[nf] = *(const bf16x8*)(&lds[cur][offB[nf]]);
#pragma unroll
    for (int mf = 0; mf < MF; ++mf)
#pragma unroll
      for (int nf = 0; nf < NF; ++nf)
        acc[mf][nf] = __builtin_amdgcn_mfma_f32_16x16x32_bf16(af[mf], bfn[nf], acc[mf][nf], 0, 0, 0);
  }

  if constexpr (OUT == 0) {
    if (z == 0) {
      bf16* C = (bf16*)Cv;
#pragma unroll
      for (int nf = 0; nf < NF; ++nf) {
        const long col = n0 + wc + nf * 16 + lr;
        const float bcol = bias0[col];
#pragma unroll
        for (int mf = 0; mf < MF; ++mf) {
          const long rowb = m0 + wr + mf * 16 + lg * 4;
#pragma unroll
          for (int r = 0; r < 4; ++r)
            C[(rowb + r) * (long)DIM + col] = (bf16)((acc[mf][nf][r] + bcol) * QSCALE);
        }
      }
    } else {
      bf16* Vt = (bf16*)Cv + NQ_;
#pragma unroll
      for (int nf = 0; nf < NF; ++nf) {
        const long col = n0 + wc + nf * 16 + lr;
        const float bcol = bias1[col];
#pragma unroll
        for (int mf = 0; mf < MF; ++mf) {
          const long rowb = m0 + wr + mf * 16 + lg * 4;
#pragma unroll
          for (int r = 0; r < 4; ++r) {
            long gr = rowb + r, bb = gr >> 12, ss = gr & 4095;
            Vt[bb * (long)(DIM * SEQ) + col * (long)SEQ + ss] = (bf16)(acc[mf][nf][r] + bcol);
          }
        }
      }
    }
  } else {
    bf16* C = (bf16*)Cv;
#pragma unroll
    for (int mf = 0; mf < MF; ++mf) {
      const long rowb = m0 + wr + mf * 16 + lg * 4;
#pragma unroll
      for (int r = 0; r < 4; ++r) {
        float rsum = 0.0f;
#pragma unroll
        for (int nf = 0; nf < NF; ++nf) {
          const long col = n0 + wc + nf * 16 + lr;
          float e = __expf(acc[mf][nf][r]);
          bf16 eb = (bf16)e;
          C[(rowb + r) * (long)N + col] = eb;
          rsum += (float)eb;
        }
        rsum += __shfl_xor(rsum, 1);
        rsum += __shfl_xor(rsum, 2);
        rsum += __shfl_xor(rsum, 4);
        rsum += __shfl_xor(rsum, 8);
        if (lr == 0) atomicAdd(rowsum + rowb + r, rsum);
      }
    }
  }
}

// ---------------------------------------------------------------------------
// pv32: O[s,d] = sum_t E[s,t]*Vt[d,t] / rowsum[s], x4 h-planes (f32).
// BM=128 (s), BN=128 (d), BK=32. 256 thr = 4 waves 2x2; per-wave 64x64 via
// 2x2 frags of mfma_f32_32x32x16_bf16 (8 MFMA / 8 ds_read_b128 per tile:
// 32 FLOP/B — fixes the 16x16 version's LDS-bound 8/6 ratio).
// A-frag: lane l -> row=l&31, k=(l>>5)*8+j. C/D: col=l&31,
// row=(reg&3)+8*(reg>>2)+4*(l>>5) [m74/m101].
// Custom XCD map: the 4 n-tiles of one m-slab run concurrently on one XCD
// so the S-slab is fetched from HBM once (L2-shared).
// 3-stage rotating pipeline as gemm3. 48KB LDS -> 3 blocks/CU.
// ---------------------------------------------------------------------------
__global__ __launch_bounds__(256, 3)
void pv32(const bf16* __restrict__ S, const bf16* __restrict__ Vt,
          float* __restrict__ out, const float* __restrict__ rowsum, int nm) {
  constexpr int ASZ = 128 * 32;
  __shared__ __align__(16) bf16 lds[3][2 * ASZ];
  const int t = threadIdx.x;
  const int l = t & 63, w = t >> 6;

  const int bid = blockIdx.x;
  const int xcd = bid & 7, j = bid >> 3;
  const int mpx = nm >> 3;                 // m-tiles per XCD
  const int mt = xcd * mpx + (j >> 2);
  const int nt = j & 3;
  const long m0 = (long)mt * 128;          // global S-row (both batches)
  const long n0 = (long)nt * 128;          // d col
  const long bb = m0 >> 12;                // batch
  const bf16* A = S + m0 * (long)SEQ;      // [8192,4096] row-major
  const bf16* B = Vt + bb * (long)DIM * SEQ + n0 * (long)SEQ;

  // staging sources (2 A + 2 B loads/thread/tile)
  const bf16* gA[2];
  const bf16* gB[2];
#pragma unroll
  for (int i = 0; i < 2; ++i) {
    int s = i * 256 + t, row = s >> 2, c = (s & 3) ^ ((row >> 1) & 3);
    gA[i] = A + row * (long)SEQ + c * 8;
    gB[i] = B + row * (long)SEQ + c * 8;
  }

  // frag ds_read offsets (elems): [frag][ks]
  const int wrb = (w >> 1) * 64, wcb = (w & 1) * 64;
  int offA[2][2], offB[2][2];
#pragma unroll
  for (int f = 0; f < 2; ++f)
#pragma unroll
    for (int ks = 0; ks < 2; ++ks) {
      int rowA = wrb + f * 32 + (l & 31);
      int rowB = wcb + f * 32 + (l & 31);
      int cb = ks * 2 + (l >> 5);
      offA[f][ks] = rowA * 32 + ((cb ^ ((rowA >> 1) & 3)) * 8);
      offB[f][ks] = ASZ + rowB * 32 + ((cb ^ ((rowB >> 1) & 3)) * 8);
    }

  auto stage = [&](int tt, int bidx) {
    const long ko = (long)tt * 32;
#pragma unroll
    for (int i = 0; i < 2; ++i)
      GLOAD_LDS16(gA[i] + ko, &lds[bidx][(i * 256 + w * 64) * 8]);
#pragma unroll
    for (int i = 0; i < 2; ++i)
      GLOAD_LDS16(gB[i] + ko, &lds[bidx][ASZ + (i * 256 + w * 64) * 8]);
  };

  f32x16 acc00 = {}, acc01 = {}, acc10 = {}, acc11 = {};
  const int NT = SEQ >> 5;  // 128

  stage(0, 0);
  stage(1, 1);
  VMCNT(4);
  __builtin_amdgcn_sched_barrier(0);
  __builtin_amdgcn_s_barrier();
  __builtin_amdgcn_sched_barrier(0);

  int cur = 0, stg = 2;
  for (int tt = 0; tt < NT; ++tt) {
    bf16x8 a[2][2], b[2][2];
#pragma unroll
    for (int f = 0; f < 2; ++f)
#pragma unroll
      for (int ks = 0; ks < 2; ++ks) {
        a[f][ks] = *(const bf16x8*)(&lds[cur][offA[f][ks]]);
        b[f][ks] = *(const bf16x8*)(&lds[cur][offB[f][ks]]);
      }
    if (tt + 2 < NT) stage(tt + 2, stg);
    __builtin_amdgcn_s_setprio(1);
#pragma unroll
    for (int ks = 0; ks < 2; ++ks) {
      acc00 = __builtin_amdgcn_mfma_f32_32x32x16_bf16(a[0][ks], b[0][ks], acc00, 0, 0, 0);
      acc01 = __builtin_amdgcn_mfma_f32_32x32x16_bf16(a[0][ks], b[1][ks], acc01, 0, 0, 0);
      acc10 = __builtin_amdgcn_mfma_f32_32x32x16_bf16(a[1][ks], b[0][ks], acc10, 0, 0, 0);
      acc11 = __builtin_amdgcn_mfma_f32_32x32x16_bf16(a[1][ks], b[1][ks], acc11, 0, 0, 0);
    }
    __builtin_amdgcn_s_setprio(0);
    if (tt + 2 < NT) {
      VMCNT(4);
    } else if (tt + 1 < NT) {
      VMCNT(0);
    }
    if (tt + 1 < NT) {
      __builtin_amdgcn_sched_barrier(0);
      __builtin_amdgcn_s_barrier();
      __builtin_amdgcn_sched_barrier(0);
    }
    cur = (cur == 2) ? 0 : cur + 1;
    stg = (stg == 2) ? 0 : stg + 1;
  }

  // epilogue: C/D col=l&31, row=(reg&3)+8*(reg>>2)+4*(l>>5)
  float* obase = out + bb * (4L * SEQ * DIM);
#pragma unroll
  for (int fm = 0; fm < 2; ++fm) {
#pragma unroll
    for (int fn = 0; fn < 2; ++fn) {
      const f32x16 av = (fm == 0) ? (fn == 0 ? acc00 : acc01)
                                  : (fn == 0 ? acc10 : acc11);
      const long col = n0 + wcb + fn * 32 + (l & 31);
#pragma unroll
      for (int reg = 0; reg < 16; ++reg) {
        const int rin = (reg & 3) + 8 * (reg >> 2) + 4 * (l >> 5);
        const long gr = m0 + wrb + fm * 32 + rin;
        const float vv = av[reg] / rowsum[gr];
        float* p = obase + (gr & 4095) * (long)DIM + col;
        p[0] = vv;
        p[1L * SEQ * DIM] = vv;
        p[2L * SEQ * DIM] = vv;
        p[3L * SEQ * DIM] = vv;
      }
    }
  }
}

// ---------------------------------------------------------------------------
// Host launch
// ---------------------------------------------------------------------------
extern "C" void kernel_launch(void* const* d_in, const int* in_sizes, int n_in,
                              void* d_out, int out_size, void* d_ws, size_t ws_size,
                              hipStream_t stream) {
  const float* q  = (const float*)d_in[0];
  const float* k  = (const float*)d_in[1];
  const float* v  = (const float*)d_in[2];
  const float* Wq = (const float*)d_in[3];
  const float* bq = (const float*)d_in[4];
  const float* Wv = (const float*)d_in[5];
  const float* bv = (const float*)d_in[6];
  float* outp = (float*)d_out;

  bf16* Qbf = (bf16*)d_ws;       // [8192, 512] scaled Q projection
  bf16* Vt  = Qbf + NQ_;         // [B, D, S] V projection transposed
  bf16* Kbf = Vt + NQ_;          // [8192, 512] k cast
  bf16* Wqb = Kbf + NQ_;
  bf16* Wvb = Wqb + NW_;
  bf16* Sbuf = Wvb + NW_;        // E = exp(scores), bf16
  const size_t baseBytes = (size_t)((char*)Sbuf - (char*)d_ws);  // 26,214,400
  const long sQK = (long)SEQ * DIM;
  const long sS  = (long)SEQ * SEQ;
  const long sO  = 4L * SEQ * DIM;
  const bool batched = ws_size >= baseBytes + 2ULL * sS * 2 + 32768;
  float* rowsum = batched ? (float*)(Sbuf + 2 * sS) : (float*)(Sbuf + sS);
  bf16* qb = Sbuf;               // cast temporaries (vb = qb + NQ_)
  bf16* vb = Sbuf + NQ_;

  cast5<<<dim3(2048), dim3(256), 0, stream>>>(q, k, v, Wq, Wv, qb, Kbf, vb, Wqb, Wvb,
                                              batched ? rowsum : nullptr);
  gemm3<128, 128, 0><<<dim3(64, 4, 2), dim3(512), 0, stream>>>(
      qb, Wqb, Qbf, bq, bv, nullptr, 512, 512, 0);
  if (batched) {
    gemm3<256, 256, 1><<<dim3(32, 16, 1), dim3(512), 0, stream>>>(
        Qbf, Kbf, Sbuf, nullptr, nullptr, rowsum, 4096, 512, sQK);
    pv32<<<dim3(256), dim3(256), 0, stream>>>(Sbuf, Vt, outp, rowsum, 64);
  } else {
    for (int b = 0; b < 2; ++b) {
      zero_f32<<<dim3(16), dim3(256), 0, stream>>>(rowsum, SEQ);
      gemm3<256, 256, 1><<<dim3(16, 16, 1), dim3(512), 0, stream>>>(
          Qbf + b * sQK, Kbf + b * sQK, Sbuf, nullptr, nullptr, rowsum, 4096, 512, sQK);
      pv32<<<dim3(128), dim3(256), 0, stream>>>(Sbuf, Vt + b * sQK, outp + b * sO,
                                                rowsum, 32);
    }
  }
}